// Round 12
// baseline (180.727 us; speedup 1.0000x reference)
//
#include <hip/hip_runtime.h>

// LSTM: B=16384, T=1024, I=1, H=2, C=4.
// 2 lanes per batch element: lane (2e+j) owns hidden unit j of element e.
//
// R12 = R10 kernel body BYTE-IDENTICAL (best: 104.1 us, 244 cy/step).
// Single variable changed: WAVE PLACEMENT. block 64 -> 512 (8 waves/block
// -> 2 waves per SIMD on each active CU), grid 512 -> 64.
// Rationale: rocprof fit shows L_step = issue(~127cy) + unfilled stalls
// (~117cy) because each wave sits ALONE on its SIMD (512 waves over 1024
// SIMDs) and in-order issue can't fill its own dependency-stall windows.
// Two co-resident waves interleave cycle-by-cycle: each fills the other's
// trans/VALU latency stalls. Expect L_step -> max(dataflow ~170, 2x issue
// ~210-230) => ~88-97 us. Waves-per-SIMD beyond 2 would be issue-bound
// (4x127 > 244): 2 is the sweet spot.
//
// Gate rows (PyTorch order): i: 0,1  f: 2,3  g: 4,5  o: 6,7
//   Ei=e^-i, Ef=e^-f, Eo=e^-o (SIG_SCALE folded), Eg=e^{2g} (TANH_SCALE).
//   c' = A/B:  A = (c*Ip)*Gp + (Eg-1)*F,  B = (Gp*F)*Ip,
//   F=1+Ef, Ip=1+Ei, Gp=1+Eg, Oo=1+Eo.
//   h' = tanh(zc)*sigma(o), zc = med3(A,-4B,4B)*rB,
//   tanh(zc) = zc*(zc^4+105zc^2+945)/(15zc^4+420zc^2+945),  D = q*Oo.

typedef float f32x2 __attribute__((ext_vector_type(2)));

static __device__ __forceinline__ float fast_exp2(float x) { return __builtin_amdgcn_exp2f(x); }
static __device__ __forceinline__ float fast_rcp(float x)  { return __builtin_amdgcn_rcpf(x); }

// Swap values between lane pairs (0<->1, 2<->3, ...) via DPP quad_perm.
static __device__ __forceinline__ float dpp_swap1(float v) {
    int i = __builtin_bit_cast(int, v);
    i = __builtin_amdgcn_mov_dpp(i, 0xB1, 0xF, 0xF, false);
    return __builtin_bit_cast(float, i);
}

#define SIG_SCALE  (-1.4426950408889634f)  // -log2(e)
#define TANH_SCALE ( 2.8853900817779268f)  // 2*log2(e)

__global__ __launch_bounds__(512) void lstm_fused8(
    const float* __restrict__ x,      // [B, T, 1]
    const float* __restrict__ W_ih,   // [8, 1]
    const float* __restrict__ W_hh,   // [8, 2]
    const float* __restrict__ b_ih,   // [8]
    const float* __restrict__ b_hh,   // [8]
    const float* __restrict__ W_fc,   // [4, 2]
    const float* __restrict__ b_fc,   // [4]
    float* __restrict__ out,          // [B, 4]
    int T)
{
    const int tid = blockIdx.x * 512 + threadIdx.x;
    const int e   = tid >> 1;          // batch element
    const int j   = tid & 1;           // hidden unit owned by this lane

    // Per-lane scaled weights for my unit's 4 gates (k: 0=i,1=f,2=g,3=o).
    // whm multiplies MY h, whp multiplies my PARTNER's h.
    float wihs[4], whm[4], whp[4], bbs[4];
#pragma unroll
    for (int k = 0; k < 4; ++k) {
        const int g = 2 * k + j;                         // gate row
        const float s = (k == 2) ? TANH_SCALE : SIG_SCALE;
        wihs[k] = s * W_ih[g];
        whm[k]  = s * W_hh[2 * g + j];
        whp[k]  = s * W_hh[2 * g + (j ^ 1)];
        bbs[k]  = s * (b_ih[g] + b_hh[g]);
    }

    // Packed views for v_pk_fma_f32 on the pre-activation math.
    f32x2 wihs2[2], whm2[2], whp2[2], bbs2[2];
#pragma unroll
    for (int q = 0; q < 2; ++q) {
        wihs2[q] = f32x2{wihs[2*q], wihs[2*q+1]};
        whm2[q]  = f32x2{whm[2*q],  whm[2*q+1]};
        whp2[q]  = f32x2{whp[2*q],  whp[2*q+1]};
        bbs2[q]  = f32x2{bbs[2*q],  bbs[2*q+1]};
    }

    float hm = 0.f;   // my unit's h
    float hp = 0.f;   // partner unit's h
    float c  = 0.f;   // my unit's c

    const float4* xv = reinterpret_cast<const float4*>(x + (size_t)e * (size_t)T);
    const int nt4 = T >> 2;

    for (int t4 = 0; t4 < nt4; ++t4) {
        const float4 xq = xv[t4];
        const float xs[4] = {xq.x, xq.y, xq.z, xq.w};

        // h-independent x-terms for 4 timesteps (packed fma, off-chain).
        f32x2 xterm[4][2];
#pragma unroll
        for (int u = 0; u < 4; ++u) {
            const f32x2 xu = f32x2{xs[u], xs[u]};
#pragma unroll
            for (int q = 0; q < 2; ++q)
                xterm[u][q] = __builtin_elementwise_fma(xu, wihs2[q], bbs2[q]);
        }

#pragma unroll
        for (int u = 0; u < 4; ++u) {
            const f32x2 hmv = f32x2{hm, hm};
            const f32x2 hpv = f32x2{hp, hp};
            // pre23 first: Eg (pre23.x) heads the critical path.
            const f32x2 pre23 = __builtin_elementwise_fma(
                whm2[1], hmv, __builtin_elementwise_fma(whp2[1], hpv, xterm[u][1]));
            const f32x2 pre01 = __builtin_elementwise_fma(
                whm2[0], hmv, __builtin_elementwise_fma(whp2[0], hpv, xterm[u][0]));

            // Chain-critical exps first: Eg, Ef, Ei; Eo has slack.
            const float Eg = fast_exp2(pre23.x);
            const float Ef = fast_exp2(pre01.y);
            const float Ei = fast_exp2(pre01.x);
            const float Eo = fast_exp2(pre23.y);

            const float Gp  = 1.f + Eg;
            const float F   = 1.f + Ef;
            const float Ip  = 1.f + Ei;
            const float Oo  = 1.f + Eo;

            const float GpF = Gp * F;
            const float GmF = fmaf(Eg, F, -F);             // (Eg-1)(1+Ef)
            const float B   = GpF * Ip;
            const float cp  = c * Ip;
            const float A   = fmaf(cp, Gp, GmF);

            // Clamp in (A,B) space BEFORE the rcp (issues during rcp wait).
            const float B4  = 4.0f * B;                    // 4.0 = inline const
            const float zA  = __builtin_amdgcn_fmed3f(A, -B4, B4);

            const float rB  = fast_rcp(B);                 // trans stage 2
            c = A * rB;                                    // next cell, off-path
            const float zc = zA * rB;                      // clamped c'

            // Pade[5/4] tanh, Horner depth 2 from uu.
            const float uu = zc * zc;
            const float p  = fmaf(uu + 105.f, uu, 945.f);
            const float q  = fmaf(fmaf(15.f, uu, 420.f), uu, 945.f);
            const float numer = zc * p;
            const float D  = q * Oo;
            const float rD = fast_rcp(D);                  // trans stage 3
            hm = numer * rD;                               // tanh(c')*sigma(o)

            hp = dpp_swap1(hm);                            // lane-pair swap
        }
    }

    // Final FC: out[e,:] = h @ W_fc^T + b_fc.  Even lane -> classes 0,1;
    // odd lane -> classes 2,3. Lane pair writes one contiguous 16B row.
    const float h0 = j ? hp : hm;
    const float h1 = j ? hm : hp;
    const int   c0 = 2 * j;
    const float o0 = fmaf(W_fc[2*c0+0], h0, fmaf(W_fc[2*c0+1], h1, b_fc[c0]));
    const float o1 = fmaf(W_fc[2*c0+2], h0, fmaf(W_fc[2*c0+3], h1, b_fc[c0+1]));
    float2 r2; r2.x = o0; r2.y = o1;
    reinterpret_cast<float2*>(out)[e * 2 + j] = r2;
}

extern "C" void kernel_launch(void* const* d_in, const int* in_sizes, int n_in,
                              void* d_out, int out_size, void* d_ws, size_t ws_size,
                              hipStream_t stream) {
    const float* x    = (const float*)d_in[0];
    const float* W_ih = (const float*)d_in[1];
    const float* W_hh = (const float*)d_in[2];
    const float* b_ih = (const float*)d_in[3];
    const float* b_hh = (const float*)d_in[4];
    const float* W_fc = (const float*)d_in[5];
    const float* b_fc = (const float*)d_in[6];
    float* out = (float*)d_out;

    const int T = 1024;
    const int B = in_sizes[0] / T;   // I == 1

    // 2 lanes/element -> 32768 threads. block=512 (8 waves) packs 2 waves
    // per SIMD on each of 64 CUs: sibling waves fill each other's
    // dependency-stall cycles (in-order solo waves cannot).
    dim3 block(512);
    dim3 grid((B * 2) / 512);        // 64 blocks
    lstm_fused8<<<grid, block, 0, stream>>>(x, W_ih, W_hh, b_ih, b_hh, W_fc, b_fc, out, T);
}

// Round 13
// 91.678 us; speedup vs baseline: 1.9713x; 1.9713x over previous
//
#include <hip/hip_runtime.h>

// LSTM: B=16384, T=1024, I=1, H=2, C=4.
// 2 lanes per batch element: lane (2e+j) owns hidden unit j of element e.
//
// R13 = R10 recurrence body BYTE-IDENTICAL (best: 104.1 us, 244 cy/step).
// Single change: x consumed through a 4-DEEP rotating register pipeline
// (prefetch distance 4 groups = 16 timesteps ahead).
// Rationale: R6's distance-1 prefetch was neutral because the compiler had
// already achieved distance-1 in R5 — and distance-1's window (~400 cy of
// compute per 4-step group) does NOT cover a cold streaming HBM load
// (~900 cy, m126). Exposed remainder ~300-500 cy/group = ~75-125 cy/step
// matches the unexplained stall residual in the 244 cy/step fit.
// Distance 4 gives a ~1150 cy window -> fully hidden.
//
// Gate rows (PyTorch order): i: 0,1  f: 2,3  g: 4,5  o: 6,7
//   Ei=e^-i, Ef=e^-f, Eo=e^-o (SIG_SCALE folded), Eg=e^{2g} (TANH_SCALE).
//   c' = A/B:  A = (c*Ip)*Gp + (Eg-1)*F,  B = (Gp*F)*Ip,
//   F=1+Ef, Ip=1+Ei, Gp=1+Eg, Oo=1+Eo.
//   h' = tanh(zc)*sigma(o), zc = med3(A,-4B,4B)*rB,
//   tanh(zc) = zc*(zc^4+105zc^2+945)/(15zc^4+420zc^2+945),  D = q*Oo.

typedef float f32x2 __attribute__((ext_vector_type(2)));

static __device__ __forceinline__ float fast_exp2(float x) { return __builtin_amdgcn_exp2f(x); }
static __device__ __forceinline__ float fast_rcp(float x)  { return __builtin_amdgcn_rcpf(x); }

// Swap values between lane pairs (0<->1, 2<->3, ...) via DPP quad_perm.
static __device__ __forceinline__ float dpp_swap1(float v) {
    int i = __builtin_bit_cast(int, v);
    i = __builtin_amdgcn_mov_dpp(i, 0xB1, 0xF, 0xF, false);
    return __builtin_bit_cast(float, i);
}

#define SIG_SCALE  (-1.4426950408889634f)  // -log2(e)
#define TANH_SCALE ( 2.8853900817779268f)  // 2*log2(e)

__global__ __launch_bounds__(64, 1) void lstm_fused9(
    const float* __restrict__ x,      // [B, T, 1]
    const float* __restrict__ W_ih,   // [8, 1]
    const float* __restrict__ W_hh,   // [8, 2]
    const float* __restrict__ b_ih,   // [8]
    const float* __restrict__ b_hh,   // [8]
    const float* __restrict__ W_fc,   // [4, 2]
    const float* __restrict__ b_fc,   // [4]
    float* __restrict__ out,          // [B, 4]
    int T)
{
    const int tid = blockIdx.x * 64 + threadIdx.x;
    const int e   = tid >> 1;          // batch element
    const int j   = tid & 1;           // hidden unit owned by this lane

    // Per-lane scaled weights for my unit's 4 gates (k: 0=i,1=f,2=g,3=o).
    // whm multiplies MY h, whp multiplies my PARTNER's h.
    float wihs[4], whm[4], whp[4], bbs[4];
#pragma unroll
    for (int k = 0; k < 4; ++k) {
        const int g = 2 * k + j;                         // gate row
        const float s = (k == 2) ? TANH_SCALE : SIG_SCALE;
        wihs[k] = s * W_ih[g];
        whm[k]  = s * W_hh[2 * g + j];
        whp[k]  = s * W_hh[2 * g + (j ^ 1)];
        bbs[k]  = s * (b_ih[g] + b_hh[g]);
    }

    // Packed views for v_pk_fma_f32 on the pre-activation math.
    f32x2 wihs2[2], whm2[2], whp2[2], bbs2[2];
#pragma unroll
    for (int q = 0; q < 2; ++q) {
        wihs2[q] = f32x2{wihs[2*q], wihs[2*q+1]};
        whm2[q]  = f32x2{whm[2*q],  whm[2*q+1]};
        whp2[q]  = f32x2{whp[2*q],  whp[2*q+1]};
        bbs2[q]  = f32x2{bbs[2*q],  bbs[2*q+1]};
    }

    float hm = 0.f;   // my unit's h
    float hp = 0.f;   // partner unit's h
    float c  = 0.f;   // my unit's c

    const float4* xv = reinterpret_cast<const float4*>(x + (size_t)e * (size_t)T);
    const int nt4 = T >> 2;            // 256 groups of 4 timesteps

    // 4-deep rotating prefetch pipeline (static slots — no dynamic indexing).
    float4 slot0 = xv[0];
    float4 slot1 = xv[1];
    float4 slot2 = xv[2];
    float4 slot3 = xv[3];

    const int nblk = nt4 >> 2;         // 64 blocks of 4 groups

    for (int bg = 0; bg < nblk; ++bg) {
        const int g0 = bg << 2;

#pragma unroll
        for (int i = 0; i < 4; ++i) {
            // Consume slot i (group g0+i), then immediately re-issue its
            // load for group g0+i+4 (clamped) — ~12 steps of compute
            // (~1150 cy) before that data is consumed next block.
            float4 xq = (i == 0) ? slot0 : (i == 1) ? slot1 : (i == 2) ? slot2 : slot3;

            const int gn = g0 + i + 4;
            const int gl = (gn < nt4) ? gn : (nt4 - 1);    // uniform clamp
            const float4 nx = xv[gl];
            if (i == 0) slot0 = nx; else if (i == 1) slot1 = nx;
            else if (i == 2) slot2 = nx; else slot3 = nx;

            const float xs[4] = {xq.x, xq.y, xq.z, xq.w};

            // h-independent x-terms for 4 timesteps (packed fma, off-chain).
            f32x2 xterm[4][2];
#pragma unroll
            for (int u = 0; u < 4; ++u) {
                const f32x2 xu = f32x2{xs[u], xs[u]};
#pragma unroll
                for (int q = 0; q < 2; ++q)
                    xterm[u][q] = __builtin_elementwise_fma(xu, wihs2[q], bbs2[q]);
            }

#pragma unroll
            for (int u = 0; u < 4; ++u) {
                const f32x2 hmv = f32x2{hm, hm};
                const f32x2 hpv = f32x2{hp, hp};
                // pre23 first: Eg (pre23.x) heads the critical path.
                const f32x2 pre23 = __builtin_elementwise_fma(
                    whm2[1], hmv, __builtin_elementwise_fma(whp2[1], hpv, xterm[u][1]));
                const f32x2 pre01 = __builtin_elementwise_fma(
                    whm2[0], hmv, __builtin_elementwise_fma(whp2[0], hpv, xterm[u][0]));

                // Chain-critical exps first: Eg, Ef, Ei; Eo has slack.
                const float Eg = fast_exp2(pre23.x);
                const float Ef = fast_exp2(pre01.y);
                const float Ei = fast_exp2(pre01.x);
                const float Eo = fast_exp2(pre23.y);

                const float Gp  = 1.f + Eg;
                const float F   = 1.f + Ef;
                const float Ip  = 1.f + Ei;
                const float Oo  = 1.f + Eo;

                const float GpF = Gp * F;
                const float GmF = fmaf(Eg, F, -F);             // (Eg-1)(1+Ef)
                const float B   = GpF * Ip;
                const float cp  = c * Ip;
                const float A   = fmaf(cp, Gp, GmF);

                // Clamp in (A,B) space BEFORE the rcp (issues during rcp wait).
                const float B4  = 4.0f * B;
                const float zA  = __builtin_amdgcn_fmed3f(A, -B4, B4);

                const float rB  = fast_rcp(B);                 // trans stage 2
                c = A * rB;                                    // next cell, off-path
                const float zc = zA * rB;                      // clamped c'

                // Pade[5/4] tanh, Horner depth 2 from uu.
                const float uu = zc * zc;
                const float p  = fmaf(uu + 105.f, uu, 945.f);
                const float q  = fmaf(fmaf(15.f, uu, 420.f), uu, 945.f);
                const float numer = zc * p;
                const float D  = q * Oo;
                const float rD = fast_rcp(D);                  // trans stage 3
                hm = numer * rD;                               // tanh(c')*sigma(o)

                hp = dpp_swap1(hm);                            // lane-pair swap
            }
        }
    }

    // Final FC: out[e,:] = h @ W_fc^T + b_fc.  Even lane -> classes 0,1;
    // odd lane -> classes 2,3. Lane pair writes one contiguous 16B row.
    const float h0 = j ? hp : hm;
    const float h1 = j ? hm : hp;
    const int   c0 = 2 * j;
    const float o0 = fmaf(W_fc[2*c0+0], h0, fmaf(W_fc[2*c0+1], h1, b_fc[c0]));
    const float o1 = fmaf(W_fc[2*c0+2], h0, fmaf(W_fc[2*c0+3], h1, b_fc[c0+1]));
    float2 r2; r2.x = o0; r2.y = o1;
    reinterpret_cast<float2*>(out)[e * 2 + j] = r2;
}

extern "C" void kernel_launch(void* const* d_in, const int* in_sizes, int n_in,
                              void* d_out, int out_size, void* d_ws, size_t ws_size,
                              hipStream_t stream) {
    const float* x    = (const float*)d_in[0];
    const float* W_ih = (const float*)d_in[1];
    const float* W_hh = (const float*)d_in[2];
    const float* b_ih = (const float*)d_in[3];
    const float* b_hh = (const float*)d_in[4];
    const float* W_fc = (const float*)d_in[5];
    const float* b_fc = (const float*)d_in[6];
    float* out = (float*)d_out;

    const int T = 1024;
    const int B = in_sizes[0] / T;   // I == 1

    dim3 block(64);
    dim3 grid((B * 2) / 64);         // 512 waves -> 2 waves/CU (R10 placement)
    lstm_fused9<<<grid, block, 0, stream>>>(x, W_ih, W_hh, b_ih, b_hh, W_fc, b_fc, out, T);
}